// Round 4
// baseline (189.136 us; speedup 1.0000x reference)
//
#include <hip/hip_runtime.h>
#include <cstdint>

typedef short  s16x8 __attribute__((ext_vector_type(8)));
typedef float  f32x4 __attribute__((ext_vector_type(4)));
typedef int    i32x4 __attribute__((ext_vector_type(4)));
typedef unsigned short u16x4 __attribute__((ext_vector_type(4)));
typedef unsigned short u16x8 __attribute__((ext_vector_type(8)));

#define OUT_F 11008
#define IN_F  4096
#define MROWS 512
#define GQ4   176128   // i32x4 elements per W_q row (704512/4)
#define HALF  5504     // o and o+HALF share a packed byte
#define RMOD  172

__device__ __forceinline__ unsigned short f2bf(float f) {
  unsigned u = __builtin_bit_cast(unsigned, f);
  return (unsigned short)((u + 0x8000u) >> 16);
}
__device__ __forceinline__ float bfbits(unsigned bits) {
  return __builtin_bit_cast(float, bits);
}

// ---- prelude: bf16-convert x and U; pack (s, -z*s) as bf16x8 per 4 cols ----
__global__ __launch_bounds__(256) void convert_k(const float* __restrict__ x,
                                                 const float* __restrict__ U,
                                                 const float* __restrict__ scale,
                                                 const float* __restrict__ zero,
                                                 unsigned short* __restrict__ xbf,
                                                 unsigned short* __restrict__ Ubf,
                                                 u16x8* __restrict__ szp) {
  int i = blockIdx.x * 256 + threadIdx.x;
  const int NX = (MROWS * IN_F) / 4;   // 524288
  const int NU = (OUT_F * 32) / 4;     // 88064
  const int NS = 704512 / 4;           // 176128
  if (i < NX + NU) {
    const float* src; unsigned short* dst; int idx;
    if (i < NX) { src = x; dst = xbf; idx = i; }
    else        { src = U; dst = Ubf; idx = i - NX; }
    f32x4 v = *(const f32x4*)(src + (size_t)idx * 4);
    u16x4 o;
    o[0] = f2bf(v[0]); o[1] = f2bf(v[1]); o[2] = f2bf(v[2]); o[3] = f2bf(v[3]);
    *(u16x4*)(dst + (size_t)idx * 4) = o;
  } else {
    int idx = i - NX - NU;
    if (idx >= NS) return;
    f32x4 s = *(const f32x4*)(scale + (size_t)idx * 4);
    f32x4 z = *(const f32x4*)(zero  + (size_t)idx * 4);
    u16x8 o;
#pragma unroll
    for (int e = 0; e < 4; ++e) {
      o[e]     = f2bf(s[e]);
      o[4 + e] = f2bf(-z[e] * s[e]);
    }
    szp[idx] = o;
  }
}

// ---- prelude 2: P = x @ V^T (512x32), split-K atomics ----
__global__ __launch_bounds__(256) void pcalc_k(const float* __restrict__ x,
                                               const float* __restrict__ V,
                                               float* __restrict__ P) {
  int m  = (blockIdx.x >> 3) * 8 + (threadIdx.x >> 5);
  int j  = threadIdx.x & 31;
  int k0 = (blockIdx.x & 7) * 512;
  const float* xr = x + (size_t)m * IN_F + k0;
  const float* vr = V + (size_t)j * IN_F + k0;
  float a = 0.f;
#pragma unroll 4
  for (int k = 0; k < 512; k += 4) {
    f32x4 xv = *(const f32x4*)(xr + k);
    f32x4 vv = *(const f32x4*)(vr + k);
    a += xv[0]*vv[0] + xv[1]*vv[1] + xv[2]*vv[2] + xv[3]*vv[3];
  }
  atomicAdd(P + m * 32 + j, a);
}

// ---- main fused dequant GEMM ----
// Tile 64m x 128o (paired: 64 low-o rows + their 64 o+HALF partners).
// LDS 48KB: A dbuf [64][64]x2 (16KB) + B dbuf [128][64]x2 (32KB), XOR-swizzled.
__global__ __launch_bounds__(256, 3) void milo_gemm(
    const unsigned short* __restrict__ xbf,
    const i32x4*          __restrict__ Wq4,
    const i32x4*          __restrict__ Szp4,
    const float*          __restrict__ Pf,
    const i32x4*          __restrict__ Ubf4,
    const float*          __restrict__ bias,
    float*                __restrict__ out)
{
  extern __shared__ __align__(16) unsigned short smem[];
  // A buffers: smem + buf*4096 shorts; B buffers: smem + 8192 + buf*8192 shorts

  const int tid  = threadIdx.x;
  const int lane = tid & 63;
  const int wid  = tid >> 6;   // 0..3
  const int wm   = wid >> 1;   // 0..1: 32-row m sub-tile
  const int wn   = wid & 1;    // 0..1: 64-col o sub-tile

  // XCD mapping: 688 = 8 XCDs x 86. gm = XCD id -> each XCD owns one m-slice.
  const int gm = blockIdx.x & 7;    // 0..7
  const int gn = blockIdx.x >> 3;   // 0..85
  const int m0 = gm * 64;
  const int o0 = gn * 64;

  // ---- W staging offsets (i32x4 units): 4 rows x 16B-chunk per thread ----
  unsigned wq_off[4], sc_off[4];
#pragma unroll
  for (int p = 0; p < 4; ++p) {
    int tr = (tid >> 4) + p * 16;          // 0..63 low-half row
    int o  = o0 + tr;
    int g  = o / RMOD;
    int r  = o - g * RMOD;
    wq_off[p] = (unsigned)g * GQ4 + (unsigned)r * 1024u + (tid & 15);
    sc_off[p] = (unsigned)r * 1024u + (tid & 15);
  }
  // ---- A staging: pre-swizzled global source (linear LDS dest) ----
  unsigned a_src[2];
#pragma unroll
  for (int it = 0; it < 2; ++it) {
    int row   = it * 32 + wid * 8 + (lane >> 3);
    int chunk = (lane & 7) ^ ((lane >> 3) & 7);     // T2 involution
    a_src[it] = (unsigned)(m0 + row) * IN_F + chunk * 8;
  }

  const int akey   = (lane & 7) << 3;   // read-side XOR key (shorts)
  const int a_base = (wm * 32 + (lane & 15)) * 64 + ((lane >> 4) * 8);
  const int b_base = (wn * 64 + (lane & 15)) * 64 + ((lane >> 4) * 8);

  f32x4 acc[2][4];
  {
    f32x4 zf = {0.f, 0.f, 0.f, 0.f};
#pragma unroll
    for (int i = 0; i < 2; ++i)
#pragma unroll
      for (int j = 0; j < 4; ++j) acc[i][j] = zf;
  }

  i32x4 wq[4], sz[4];
  f32x4 pf[4]; i32x4 uu[2];

  auto issueA = [&](int buf, int k0s) {
    unsigned short* Adst = smem + buf * 4096;
#pragma unroll
    for (int it = 0; it < 2; ++it) {
      __builtin_amdgcn_global_load_lds(
          (const __attribute__((address_space(1))) unsigned int*)(xbf + a_src[it] + k0s),
          (__attribute__((address_space(3))) unsigned int*)(Adst + (it * 32 + wid * 8) * 64),
          16, 0, 0);
    }
  };
  auto loadB = [&](int kq) {   // kq in i32x4 units (16 per K-tile)
#pragma unroll
    for (int p = 0; p < 4; ++p) {
      wq[p] = Wq4[wq_off[p] + kq];
      sz[p] = Szp4[sc_off[p] + kq];
    }
  };
  auto writeB = [&](int buf) {
    unsigned short* Bn = smem + 8192 + buf * 8192;
#pragma unroll
    for (int p = 0; p < 4; ++p) {
      int tr   = (tid >> 4) + p * 16;
      int scol = ((tid & 15) * 4) ^ ((tr & 7) << 3);
      unsigned a0 = (unsigned)sz[p][0], a1 = (unsigned)sz[p][1];
      unsigned a2 = (unsigned)sz[p][2], a3 = (unsigned)sz[p][3];
      float sA[4] = { bfbits(a0 << 16), bfbits(a0 & 0xFFFF0000u),
                      bfbits(a1 << 16), bfbits(a1 & 0xFFFF0000u) };
      float mA[4] = { bfbits(a2 << 16), bfbits(a2 & 0xFFFF0000u),
                      bfbits(a3 << 16), bfbits(a3 & 0xFFFF0000u) };
      u16x4 h4, l4;
#pragma unroll
      for (int e = 0; e < 4; ++e) {
        int v = wq[p][e];
        float qh = (float)((v >> 4) & 0xF);
        float ql = (float)(v & 0xF);
        h4[e] = f2bf(__builtin_fmaf(qh, sA[e], mA[e]));
        l4[e] = f2bf(__builtin_fmaf(ql, sA[e], mA[e]));
      }
      *(u16x4*)(Bn + tr * 64 + scol)        = h4;   // hi nibble -> o0+tr
      *(u16x4*)(Bn + (tr + 64) * 64 + scol) = l4;   // lo nibble -> o0+HALF+tr
    }
  };
  auto loadF = [&]() {
    int row = tid >> 2, h4 = tid & 3;
    if (h4 < 2) {
#pragma unroll
      for (int q = 0; q < 4; ++q)
        pf[q] = *(const f32x4*)(Pf + (m0 + row) * 32 + h4 * 16 + q * 4);
    }
    int rw = tid >> 1, h = tid & 1;
    int oc = (rw < 64) ? (o0 + rw) : (HALF + o0 + rw - 64);
#pragma unroll
    for (int q = 0; q < 2; ++q)
      uu[q] = Ubf4[oc * 4 + h * 2 + q];
  };
  auto writeF = [&](int buf) {
    unsigned short* An = smem + buf * 4096;
    unsigned short* Bn = smem + 8192 + buf * 8192;
    i32x4 zi = {0, 0, 0, 0};
    {
      int row = tid >> 2, h4 = tid & 3;
      int key = (row & 7) << 3;
      if (h4 < 2) {
#pragma unroll
        for (int q = 0; q < 4; ++q) {
          u16x4 t4;
          t4[0] = f2bf(pf[q][0]); t4[1] = f2bf(pf[q][1]);
          t4[2] = f2bf(pf[q][2]); t4[3] = f2bf(pf[q][3]);
          *(u16x4*)(An + row * 64 + ((h4 * 16 + q * 4) ^ key)) = t4;
        }
      } else {
#pragma unroll
        for (int q = 0; q < 4; ++q)
          *(u16x4*)(An + row * 64 + (((h4 - 2) * 16 + 32 + q * 4) ^ key)) =
              *(u16x4*)&zi;
      }
    }
    {
      int rw = tid >> 1, h = tid & 1;
      int key = (rw & 7) << 3;
#pragma unroll
      for (int q = 0; q < 2; ++q)
        *(i32x4*)(Bn + rw * 64 + ((h * 16 + q * 8) ^ key)) = uu[q];
#pragma unroll
      for (int q = 0; q < 2; ++q)
        *(i32x4*)(Bn + rw * 64 + ((32 + h * 16 + q * 8) ^ key)) = zi;
    }
  };
  auto compute = [&](int buf) {
    const unsigned short* Ac = smem + buf * 4096;
    const unsigned short* Bc = smem + 8192 + buf * 8192;
#pragma unroll
    for (int kk = 0; kk < 64; kk += 32) {
      s16x8 av[2], bv[4];
#pragma unroll
      for (int f = 0; f < 2; ++f)
        av[f] = *(const s16x8*)(Ac + ((a_base + f * 1024 + kk) ^ akey));
#pragma unroll
      for (int f = 0; f < 4; ++f)
        bv[f] = *(const s16x8*)(Bc + ((b_base + f * 1024 + kk) ^ akey));
#pragma unroll
      for (int i = 0; i < 2; ++i)
#pragma unroll
        for (int j = 0; j < 4; ++j)
          acc[i][j] = __builtin_amdgcn_mfma_f32_16x16x32_bf16(av[i], bv[j], acc[i][j], 0, 0, 0);
    }
  };

  // ---- prologue ----
  loadB(0);
  issueA(0, 0);
  writeB(0);
  __syncthreads();

  // ---- main K loop: 64 tiles of BK=64 ----
  for (int t = 0; t < 63; ++t) {
    int cur = t & 1, nxt = cur ^ 1;
    loadB((t + 1) * 16);
    issueA(nxt, (t + 1) * 64);
    compute(cur);
    writeB(nxt);
    __syncthreads();
  }
  // ---- tile 63 + low-rank extra K-step ----
  loadF();
  compute(1);
  writeF(0);
  __syncthreads();
  compute(0);

  // ---- epilogue: bias + store ----
#pragma unroll
  for (int fn = 0; fn < 4; ++fn) {
    int c = wn * 64 + fn * 16 + (lane & 15);
    int o = (c < 64) ? (o0 + c) : (HALF + o0 + (c - 64));
    float bv = bias[o];
#pragma unroll
    for (int fm = 0; fm < 2; ++fm) {
      int m = m0 + wm * 32 + fm * 16 + ((lane >> 4) << 2);
#pragma unroll
      for (int j = 0; j < 4; ++j)
        out[(size_t)(m + j) * OUT_F + o] = acc[fm][fn][j] + bv;
    }
  }
}

extern "C" void kernel_launch(void* const* d_in, const int* in_sizes, int n_in,
                              void* d_out, int out_size, void* d_ws, size_t ws_size,
                              hipStream_t stream) {
  const float* x     = (const float*)d_in[0];
  const int*   Wq    = (const int*)d_in[1];
  const float* scale = (const float*)d_in[2];
  const float* zero  = (const float*)d_in[3];
  const float* U     = (const float*)d_in[4];
  const float* V     = (const float*)d_in[5];
  const float* bias  = (const float*)d_in[6];
  float* out = (float*)d_out;

  unsigned short* xbf = (unsigned short*)d_ws;                 // 4 MB
  unsigned short* Ubf = xbf + (size_t)MROWS * IN_F;            // 704 KB
  float*          P   = (float*)(Ubf + (size_t)OUT_F * 32);    // 64 KB
  u16x8*          szp = (u16x8*)(P + (size_t)MROWS * 32);      // 2.75 MB

  (void)hipMemsetAsync(P, 0, (size_t)MROWS * 32 * sizeof(float), stream);
  convert_k<<<3080, 256, 0, stream>>>(x, U, scale, zero, xbf, Ubf, szp);
  pcalc_k<<<512, 256, 0, stream>>>(x, V, P);
  milo_gemm<<<688, 256, 49152, stream>>>(xbf, (const i32x4*)Wq,
                                         (const i32x4*)szp, P,
                                         (const i32x4*)Ubf, bias, out);
}

// Round 5
// 169.251 us; speedup vs baseline: 1.1175x; 1.1175x over previous
//
#include <hip/hip_runtime.h>
#include <cstdint>

typedef short  s16x8 __attribute__((ext_vector_type(8)));
typedef float  f32x4 __attribute__((ext_vector_type(4)));
typedef int    i32x4 __attribute__((ext_vector_type(4)));
typedef unsigned short u16x4 __attribute__((ext_vector_type(4)));
typedef unsigned short u16x8 __attribute__((ext_vector_type(8)));

#define OUT_F 11008
#define IN_F  4096
#define MROWS 512
#define GQ4   176128   // i32x4 elements per W_q row (704512/4)
#define HALF  5504     // o and o+HALF share a packed byte
#define RMOD  172

__device__ __forceinline__ unsigned short f2bf(float f) {
  unsigned u = __builtin_bit_cast(unsigned, f);
  return (unsigned short)((u + 0x8000u) >> 16);
}
__device__ __forceinline__ float bfbits(unsigned bits) {
  return __builtin_bit_cast(float, bits);
}

// ---- prelude: bf16-convert x and U; pack (s, -z*s) as bf16x8 per 4 cols ----
__global__ __launch_bounds__(256) void convert_k(const float* __restrict__ x,
                                                 const float* __restrict__ U,
                                                 const float* __restrict__ scale,
                                                 const float* __restrict__ zero,
                                                 unsigned short* __restrict__ xbf,
                                                 unsigned short* __restrict__ Ubf,
                                                 u16x8* __restrict__ szp) {
  int i = blockIdx.x * 256 + threadIdx.x;
  const int NX = (MROWS * IN_F) / 4;   // 524288
  const int NU = (OUT_F * 32) / 4;     // 88064
  const int NS = 704512 / 4;           // 176128
  if (i < NX + NU) {
    const float* src; unsigned short* dst; int idx;
    if (i < NX) { src = x; dst = xbf; idx = i; }
    else        { src = U; dst = Ubf; idx = i - NX; }
    f32x4 v = *(const f32x4*)(src + (size_t)idx * 4);
    u16x4 o;
    o[0] = f2bf(v[0]); o[1] = f2bf(v[1]); o[2] = f2bf(v[2]); o[3] = f2bf(v[3]);
    *(u16x4*)(dst + (size_t)idx * 4) = o;
  } else {
    int idx = i - NX - NU;
    if (idx >= NS) return;
    f32x4 s = *(const f32x4*)(scale + (size_t)idx * 4);
    f32x4 z = *(const f32x4*)(zero  + (size_t)idx * 4);
    u16x8 o;
#pragma unroll
    for (int e = 0; e < 4; ++e) {
      o[e]     = f2bf(s[e]);
      o[4 + e] = f2bf(-z[e] * s[e]);
    }
    szp[idx] = o;
  }
}

// ---- prelude 2: P = x @ V^T (512x32), split-K atomics ----
__global__ __launch_bounds__(256) void pcalc_k(const float* __restrict__ x,
                                               const float* __restrict__ V,
                                               float* __restrict__ P) {
  int m  = (blockIdx.x >> 3) * 8 + (threadIdx.x >> 5);
  int j  = threadIdx.x & 31;
  int k0 = (blockIdx.x & 7) * 512;
  const float* xr = x + (size_t)m * IN_F + k0;
  const float* vr = V + (size_t)j * IN_F + k0;
  float a = 0.f;
#pragma unroll 4
  for (int k = 0; k < 512; k += 4) {
    f32x4 xv = *(const f32x4*)(xr + k);
    f32x4 vv = *(const f32x4*)(vr + k);
    a += xv[0]*vv[0] + xv[1]*vv[1] + xv[2]*vv[2] + xv[3]*vv[3];
  }
  atomicAdd(P + m * 32 + j, a);
}

// ---- main fused dequant GEMM ----
// Tile 64m x 128o (paired: 64 low-o rows + their 64 o+HALF partners).
// LDS 48KB: A dbuf [64][64]x2 (16KB) + B dbuf [128][64]x2 (32KB), XOR-swizzled.
// Block mapping: XCD x (= b&7, dispatch round-robin) owns L in [86x, 86x+86)
// -> a CONTIGUOUS gn range with ALL 8 m-slices per gn on the same XCD, so
// each W_q line is fetched by exactly one L2 (round-3 traffic property)
// while keeping 688-block co-residency (round-4 occupancy property).
__global__ __launch_bounds__(256, 3) void milo_gemm(
    const unsigned short* __restrict__ xbf,
    const i32x4*          __restrict__ Wq4,
    const i32x4*          __restrict__ Szp4,
    const float*          __restrict__ Pf,
    const i32x4*          __restrict__ Ubf4,
    const float*          __restrict__ bias,
    float*                __restrict__ out)
{
  extern __shared__ __align__(16) unsigned short smem[];
  // A buffers: smem + buf*4096 shorts; B buffers: smem + 8192 + buf*8192 shorts

  const int tid  = threadIdx.x;
  const int lane = tid & 63;
  const int wid  = tid >> 6;   // 0..3
  const int wm   = wid >> 1;   // 0..1: 32-row m sub-tile
  const int wn   = wid & 1;    // 0..1: 64-col o sub-tile

  const int b  = blockIdx.x;
  const int L  = (b & 7) * 86 + (b >> 3);   // bijective: XCD-contiguous work id
  const int gn = L >> 3;                    // 0..85
  const int gm = L & 7;                     // 0..7
  const int m0 = gm * 64;
  const int o0 = gn * 64;

  // ---- W staging offsets (i32x4 units): 4 rows x 16B-chunk per thread ----
  unsigned wq_off[4], sc_off[4];
#pragma unroll
  for (int p = 0; p < 4; ++p) {
    int tr = (tid >> 4) + p * 16;          // 0..63 low-half row
    int o  = o0 + tr;
    int g  = o / RMOD;
    int r  = o - g * RMOD;
    wq_off[p] = (unsigned)g * GQ4 + (unsigned)r * 1024u + (tid & 15);
    sc_off[p] = (unsigned)r * 1024u + (tid & 15);
  }
  // ---- A staging: pre-swizzled global source (linear LDS dest) ----
  unsigned a_src[2];
#pragma unroll
  for (int it = 0; it < 2; ++it) {
    int row   = it * 32 + wid * 8 + (lane >> 3);
    int chunk = (lane & 7) ^ ((lane >> 3) & 7);     // T2 involution
    a_src[it] = (unsigned)(m0 + row) * IN_F + chunk * 8;
  }

  const int akey   = (lane & 7) << 3;   // read-side XOR key (shorts)
  const int a_base = (wm * 32 + (lane & 15)) * 64 + ((lane >> 4) * 8);
  const int b_base = (wn * 64 + (lane & 15)) * 64 + ((lane >> 4) * 8);

  f32x4 acc[2][4];
  {
    f32x4 zf = {0.f, 0.f, 0.f, 0.f};
#pragma unroll
    for (int i = 0; i < 2; ++i)
#pragma unroll
      for (int j = 0; j < 4; ++j) acc[i][j] = zf;
  }

  i32x4 wq[4], sz[4];
  f32x4 pf[4]; i32x4 uu[2];

  auto issueA = [&](int buf, int k0s) {
    unsigned short* Adst = smem + buf * 4096;
#pragma unroll
    for (int it = 0; it < 2; ++it) {
      __builtin_amdgcn_global_load_lds(
          (const __attribute__((address_space(1))) unsigned int*)(xbf + a_src[it] + k0s),
          (__attribute__((address_space(3))) unsigned int*)(Adst + (it * 32 + wid * 8) * 64),
          16, 0, 0);
    }
  };
  auto loadB = [&](int kq) {   // kq in i32x4 units (16 per K-tile)
#pragma unroll
    for (int p = 0; p < 4; ++p) {
      wq[p] = Wq4[wq_off[p] + kq];
      sz[p] = Szp4[sc_off[p] + kq];
    }
  };
  auto writeB = [&](int buf) {
    unsigned short* Bn = smem + 8192 + buf * 8192;
#pragma unroll
    for (int p = 0; p < 4; ++p) {
      int tr   = (tid >> 4) + p * 16;
      int scol = ((tid & 15) * 4) ^ ((tr & 7) << 3);
      unsigned a0 = (unsigned)sz[p][0], a1 = (unsigned)sz[p][1];
      unsigned a2 = (unsigned)sz[p][2], a3 = (unsigned)sz[p][3];
      float sA[4] = { bfbits(a0 << 16), bfbits(a0 & 0xFFFF0000u),
                      bfbits(a1 << 16), bfbits(a1 & 0xFFFF0000u) };
      float mA[4] = { bfbits(a2 << 16), bfbits(a2 & 0xFFFF0000u),
                      bfbits(a3 << 16), bfbits(a3 & 0xFFFF0000u) };
      u16x4 h4, l4;
#pragma unroll
      for (int e = 0; e < 4; ++e) {
        int v = wq[p][e];
        float qh = (float)((v >> 4) & 0xF);
        float ql = (float)(v & 0xF);
        h4[e] = f2bf(__builtin_fmaf(qh, sA[e], mA[e]));
        l4[e] = f2bf(__builtin_fmaf(ql, sA[e], mA[e]));
      }
      *(u16x4*)(Bn + tr * 64 + scol)        = h4;   // hi nibble -> o0+tr
      *(u16x4*)(Bn + (tr + 64) * 64 + scol) = l4;   // lo nibble -> o0+HALF+tr
    }
  };
  auto loadF = [&]() {
    int row = tid >> 2, h4 = tid & 3;
    if (h4 < 2) {
#pragma unroll
      for (int q = 0; q < 4; ++q)
        pf[q] = *(const f32x4*)(Pf + (m0 + row) * 32 + h4 * 16 + q * 4);
    }
    int rw = tid >> 1, h = tid & 1;
    int oc = (rw < 64) ? (o0 + rw) : (HALF + o0 + rw - 64);
#pragma unroll
    for (int q = 0; q < 2; ++q)
      uu[q] = Ubf4[oc * 4 + h * 2 + q];
  };
  auto writeF = [&](int buf) {
    unsigned short* An = smem + buf * 4096;
    unsigned short* Bn = smem + 8192 + buf * 8192;
    i32x4 zi = {0, 0, 0, 0};
    {
      int row = tid >> 2, h4 = tid & 3;
      int key = (row & 7) << 3;
      if (h4 < 2) {
#pragma unroll
        for (int q = 0; q < 4; ++q) {
          u16x4 t4;
          t4[0] = f2bf(pf[q][0]); t4[1] = f2bf(pf[q][1]);
          t4[2] = f2bf(pf[q][2]); t4[3] = f2bf(pf[q][3]);
          *(u16x4*)(An + row * 64 + ((h4 * 16 + q * 4) ^ key)) = t4;
        }
      } else {
#pragma unroll
        for (int q = 0; q < 4; ++q)
          *(u16x4*)(An + row * 64 + (((h4 - 2) * 16 + 32 + q * 4) ^ key)) =
              *(u16x4*)&zi;
      }
    }
    {
      int rw = tid >> 1, h = tid & 1;
      int key = (rw & 7) << 3;
#pragma unroll
      for (int q = 0; q < 2; ++q)
        *(i32x4*)(Bn + rw * 64 + ((h * 16 + q * 8) ^ key)) = uu[q];
#pragma unroll
      for (int q = 0; q < 2; ++q)
        *(i32x4*)(Bn + rw * 64 + ((32 + h * 16 + q * 8) ^ key)) = zi;
    }
  };
  auto compute = [&](int buf) {
    const unsigned short* Ac = smem + buf * 4096;
    const unsigned short* Bc = smem + 8192 + buf * 8192;
#pragma unroll
    for (int kk = 0; kk < 64; kk += 32) {
      s16x8 av[2], bv[4];
#pragma unroll
      for (int f = 0; f < 2; ++f)
        av[f] = *(const s16x8*)(Ac + ((a_base + f * 1024 + kk) ^ akey));
#pragma unroll
      for (int f = 0; f < 4; ++f)
        bv[f] = *(const s16x8*)(Bc + ((b_base + f * 1024 + kk) ^ akey));
#pragma unroll
      for (int i = 0; i < 2; ++i)
#pragma unroll
        for (int j = 0; j < 4; ++j)
          acc[i][j] = __builtin_amdgcn_mfma_f32_16x16x32_bf16(av[i], bv[j], acc[i][j], 0, 0, 0);
    }
  };

  // ---- prologue ----
  loadB(0);
  issueA(0, 0);
  writeB(0);
  __syncthreads();

  // ---- main K loop: 64 tiles of BK=64 ----
  for (int t = 0; t < 63; ++t) {
    int cur = t & 1, nxt = cur ^ 1;
    loadB((t + 1) * 16);
    issueA(nxt, (t + 1) * 64);
    compute(cur);
    writeB(nxt);
    __syncthreads();
  }
  // ---- tile 63 + low-rank extra K-step ----
  loadF();
  compute(1);
  writeF(0);
  __syncthreads();
  compute(0);

  // ---- epilogue: bias + store ----
#pragma unroll
  for (int fn = 0; fn < 4; ++fn) {
    int c = wn * 64 + fn * 16 + (lane & 15);
    int o = (c < 64) ? (o0 + c) : (HALF + o0 + (c - 64));
    float bv = bias[o];
#pragma unroll
    for (int fm = 0; fm < 2; ++fm) {
      int m = m0 + wm * 32 + fm * 16 + ((lane >> 4) << 2);
#pragma unroll
      for (int j = 0; j < 4; ++j)
        out[(size_t)(m + j) * OUT_F + o] = acc[fm][fn][j] + bv;
    }
  }
}

extern "C" void kernel_launch(void* const* d_in, const int* in_sizes, int n_in,
                              void* d_out, int out_size, void* d_ws, size_t ws_size,
                              hipStream_t stream) {
  const float* x     = (const float*)d_in[0];
  const int*   Wq    = (const int*)d_in[1];
  const float* scale = (const float*)d_in[2];
  const float* zero  = (const float*)d_in[3];
  const float* U     = (const float*)d_in[4];
  const float* V     = (const float*)d_in[5];
  const float* bias  = (const float*)d_in[6];
  float* out = (float*)d_out;

  unsigned short* xbf = (unsigned short*)d_ws;                 // 4 MB
  unsigned short* Ubf = xbf + (size_t)MROWS * IN_F;            // 704 KB
  float*          P   = (float*)(Ubf + (size_t)OUT_F * 32);    // 64 KB
  u16x8*          szp = (u16x8*)(P + (size_t)MROWS * 32);      // 2.75 MB

  (void)hipMemsetAsync(P, 0, (size_t)MROWS * 32 * sizeof(float), stream);
  convert_k<<<3080, 256, 0, stream>>>(x, U, scale, zero, xbf, Ubf, szp);
  pcalc_k<<<512, 256, 0, stream>>>(x, V, P);
  milo_gemm<<<688, 256, 49152, stream>>>(xbf, (const i32x4*)Wq,
                                         (const i32x4*)szp, P,
                                         (const i32x4*)Ubf, bias, out);
}

// Round 6
// 140.799 us; speedup vs baseline: 1.3433x; 1.2021x over previous
//
#include <hip/hip_runtime.h>
#include <cstdint>

typedef short  s16x8 __attribute__((ext_vector_type(8)));
typedef float  f32x4 __attribute__((ext_vector_type(4)));
typedef int    i32x4 __attribute__((ext_vector_type(4)));
typedef int    i32x2 __attribute__((ext_vector_type(2)));
typedef unsigned short u16x4 __attribute__((ext_vector_type(4)));

#define OUT_F 11008
#define IN_F  4096
#define MROWS 512
#define GQ4   176128   // i32x4 elements per W_q row (704512/4)
#define HALF  5504
#define RMOD  172

__device__ __forceinline__ unsigned short f2bf(float f) {
  unsigned u = __builtin_bit_cast(unsigned, f);
  return (unsigned short)((u + 0x8000u) >> 16);
}
__device__ __forceinline__ float bfbits(unsigned bits) {
  return __builtin_bit_cast(float, bits);
}
__device__ __forceinline__ unsigned cvtpk(float a, float b) {
  unsigned r;
  asm("v_cvt_pk_bf16_f32 %0, %1, %2" : "=v"(r) : "v"(a), "v"(b));
  return r;   // lo = bf16(a), hi = bf16(b)
}

// ---- prelude: bf16 x and U; f32 table mz = -(128+z)*s ----
__global__ __launch_bounds__(256) void convert_k(const float* __restrict__ x,
                                                 const float* __restrict__ U,
                                                 const float* __restrict__ scale,
                                                 const float* __restrict__ zero,
                                                 unsigned short* __restrict__ xbf,
                                                 unsigned short* __restrict__ Ubf,
                                                 f32x4* __restrict__ mz) {
  int i = blockIdx.x * 256 + threadIdx.x;
  const int NX = (MROWS * IN_F) / 4;   // 524288
  const int NU = (OUT_F * 32) / 4;     // 88064
  const int NS = 704512 / 4;           // 176128
  if (i < NX + NU) {
    const float* src; unsigned short* dst; int idx;
    if (i < NX) { src = x; dst = xbf; idx = i; }
    else        { src = U; dst = Ubf; idx = i - NX; }
    f32x4 v = *(const f32x4*)(src + (size_t)idx * 4);
    u16x4 o;
    o[0] = f2bf(v[0]); o[1] = f2bf(v[1]); o[2] = f2bf(v[2]); o[3] = f2bf(v[3]);
    *(u16x4*)(dst + (size_t)idx * 4) = o;
  } else {
    int idx = i - NX - NU;
    if (idx >= NS) return;
    f32x4 s = *(const f32x4*)(scale + (size_t)idx * 4);
    f32x4 z = *(const f32x4*)(zero  + (size_t)idx * 4);
    f32x4 m;
#pragma unroll
    for (int e = 0; e < 4; ++e) m[e] = -(z[e] + 128.f) * s[e];
    mz[idx] = m;
  }
}

// ---- prelude 2: P = x @ V^T (512x32), split-K atomics ----
__global__ __launch_bounds__(256) void pcalc_k(const float* __restrict__ x,
                                               const float* __restrict__ V,
                                               float* __restrict__ P) {
  int m  = (blockIdx.x >> 3) * 8 + (threadIdx.x >> 5);
  int j  = threadIdx.x & 31;
  int k0 = (blockIdx.x & 7) * 512;
  const float* xr = x + (size_t)m * IN_F + k0;
  const float* vr = V + (size_t)j * IN_F + k0;
  float a = 0.f;
#pragma unroll 4
  for (int k = 0; k < 512; k += 4) {
    f32x4 xv = *(const f32x4*)(xr + k);
    f32x4 vv = *(const f32x4*)(vr + k);
    a += xv[0]*vv[0] + xv[1]*vv[1] + xv[2]*vv[2] + xv[3]*vv[3];
  }
  atomicAdd(P + m * 32 + j, a);
}

// ---- main fused dequant GEMM ----
// Tile 128m x 64o (32 low-o rows + their 32 o+HALF partners).
// LDS 48KB: A dbuf [128][64]x2 (32KB) + B dbuf [64][64]x2 (16KB), XOR-swizzled.
// Grid 688 = 8 XCD x 86: XCD x owns L in [86x,86x+86) -> contiguous gn range,
// all 4 m-slices of a gn on one XCD (single-L2 W_q fetch, round-5 property).
// Dequant redundancy: 4x (was 8x); magic-const f32 dequant + cvt_pk packing.
__global__ __launch_bounds__(256, 3) void milo_gemm(
    const unsigned short* __restrict__ xbf,
    const i32x4*          __restrict__ Wq4,
    const f32x4*          __restrict__ Sc4,
    const f32x4*          __restrict__ Mz4,
    const float*          __restrict__ Pf,
    const i32x4*          __restrict__ Ubf4,
    const float*          __restrict__ bias,
    float*                __restrict__ out)
{
  extern __shared__ __align__(16) unsigned short smem[];
  // A bufs: smem + buf*8192 shorts; B bufs: smem + 16384 + buf*4096 shorts

  const int tid  = threadIdx.x;
  const int lane = tid & 63;
  const int wid  = tid >> 6;
  const int wm   = wid >> 1;   // 0..1: 64-row m sub-tile
  const int wn   = wid & 1;    // 0..1: 32-row B sub-tile

  const int b  = blockIdx.x;
  const int L  = (b & 7) * 86 + (b >> 3);
  const int gn = L >> 2;          // 0..171
  const int gm = L & 3;           // 0..3
  const int m0 = gm * 128;
  const int o0 = gn * 32;

  // ---- W staging offsets: p in {0,1}, byte-row tr = (tid>>4)+p*16 (0..31) ----
  unsigned wq_off[2], sc_off[2];
#pragma unroll
  for (int p = 0; p < 2; ++p) {
    int tr = (tid >> 4) + p * 16;
    int o  = o0 + tr;
    int g  = o / RMOD;
    int r  = o - g * RMOD;
    wq_off[p] = (unsigned)g * GQ4 + (unsigned)r * 1024u + (tid & 15);
    sc_off[p] = (unsigned)r * 1024u + (tid & 15);
  }
  // ---- A staging: pre-swizzled global source, linear LDS dest ----
  unsigned a_src[4];
#pragma unroll
  for (int it = 0; it < 4; ++it) {
    int row   = it * 32 + wid * 8 + (lane >> 3);
    int chunk = (lane & 7) ^ ((lane >> 3) & 7);
    a_src[it] = (unsigned)(m0 + row) * IN_F + chunk * 8;
  }

  const int akey   = (lane & 7) << 3;
  const int a_base = (wm * 64 + (lane & 15)) * 64 + ((lane >> 4) * 8);
  const int b_base = (wn * 32 + (lane & 15)) * 64 + ((lane >> 4) * 8);

  f32x4 acc[4][2];
  {
    f32x4 zf = {0.f, 0.f, 0.f, 0.f};
#pragma unroll
    for (int i = 0; i < 4; ++i)
#pragma unroll
      for (int j = 0; j < 2; ++j) acc[i][j] = zf;
  }

  i32x4 wq[2]; f32x4 s4[2], mz4[2];
  f32x4 pf[4]; i32x4 uuF;

  auto issueA = [&](int buf, int k0s) {
    unsigned short* Adst = smem + buf * 8192;
#pragma unroll
    for (int it = 0; it < 4; ++it) {
      __builtin_amdgcn_global_load_lds(
          (const __attribute__((address_space(1))) unsigned int*)(xbf + a_src[it] + k0s),
          (__attribute__((address_space(3))) unsigned int*)(Adst + (it * 32 + wid * 8) * 64),
          16, 0, 0);
    }
  };
  auto loadB = [&](int kq) {   // kq in 16B units (16 per K-tile)
#pragma unroll
    for (int p = 0; p < 2; ++p) {
      wq[p]  = Wq4[wq_off[p] + kq];
      s4[p]  = Sc4[sc_off[p] + kq];
      mz4[p] = Mz4[sc_off[p] + kq];
    }
  };
  auto writeB = [&](int buf) {
    unsigned short* Bn = smem + 16384 + buf * 4096;
#pragma unroll
    for (int p = 0; p < 2; ++p) {
      int tr   = (tid >> 4) + p * 16;
      int scol = ((tid & 15) * 4) ^ ((tr & 7) << 3);
      float h[4], l[4];
#pragma unroll
      for (int e = 0; e < 4; ++e) {
        int v = wq[p][e];
        // magic: 0x43000000 | (n<<16) is exactly f32(128+n) for n<16
        float qh = bfbits(0x43000000u | (((unsigned)v & 0xF0u) << 12));
        float ql = bfbits(0x43000000u | (((unsigned)v & 0x0Fu) << 16));
        h[e] = __builtin_fmaf(qh, s4[p][e], mz4[p][e]);
        l[e] = __builtin_fmaf(ql, s4[p][e], mz4[p][e]);
      }
      i32x2 hh = { (int)cvtpk(h[0], h[1]), (int)cvtpk(h[2], h[3]) };
      i32x2 ll = { (int)cvtpk(l[0], l[1]), (int)cvtpk(l[2], l[3]) };
      *(i32x2*)(Bn + tr * 64 + scol)        = hh;   // hi nibble -> o0+tr
      *(i32x2*)(Bn + (tr + 32) * 64 + scol) = ll;   // lo nibble -> o0+HALF+tr
    }
  };
  auto loadF = [&]() {
    int row = tid >> 1, h = tid & 1;
#pragma unroll
    for (int q = 0; q < 4; ++q)
      pf[q] = *(const f32x4*)(Pf + (m0 + row) * 32 + h * 16 + q * 4);
    int rw = tid >> 2, h4 = tid & 3;
    int oc = (rw < 32) ? (o0 + rw) : (HALF + o0 + rw - 32);
    uuF = Ubf4[oc * 4 + h4];
  };
  auto writeF = [&](int buf) {
    unsigned short* An = smem + buf * 8192;
    unsigned short* Bn = smem + 16384 + buf * 4096;
    i32x4 zi = {0, 0, 0, 0};
    {
      int row = tid >> 1, h = tid & 1;
      int key = (row & 7) << 3;
#pragma unroll
      for (int q = 0; q < 4; ++q) {
        i32x2 t2 = { (int)cvtpk(pf[q][0], pf[q][1]),
                     (int)cvtpk(pf[q][2], pf[q][3]) };
        *(i32x2*)(An + row * 64 + ((h * 16 + q * 4) ^ key)) = t2;
      }
#pragma unroll
      for (int q = 0; q < 2; ++q)
        *(i32x4*)(An + row * 64 + ((32 + h * 16 + q * 8) ^ key)) = zi;
    }
    {
      int rw = tid >> 2, h4 = tid & 3;
      int key = (rw & 7) << 3;
      *(i32x4*)(Bn + rw * 64 + ((h4 * 8) ^ key))      = uuF;
      *(i32x4*)(Bn + rw * 64 + ((32 + h4 * 8) ^ key)) = zi;
    }
  };
  auto compute = [&](int buf) {
    const unsigned short* Ac = smem + buf * 8192;
    const unsigned short* Bc = smem + 16384 + buf * 4096;
#pragma unroll
    for (int kk = 0; kk < 64; kk += 32) {
      s16x8 av[4], bv[2];
#pragma unroll
      for (int f = 0; f < 4; ++f)
        av[f] = *(const s16x8*)(Ac + ((a_base + f * 1024 + kk) ^ akey));
#pragma unroll
      for (int f = 0; f < 2; ++f)
        bv[f] = *(const s16x8*)(Bc + ((b_base + f * 1024 + kk) ^ akey));
#pragma unroll
      for (int i = 0; i < 4; ++i)
#pragma unroll
        for (int j = 0; j < 2; ++j)
          acc[i][j] = __builtin_amdgcn_mfma_f32_16x16x32_bf16(av[i], bv[j], acc[i][j], 0, 0, 0);
    }
  };

  // ---- prologue ----
  loadB(0);
  issueA(0, 0);
  writeB(0);
  __syncthreads();

  // ---- main K loop: 64 tiles of BK=64 ----
  for (int t = 0; t < 63; ++t) {
    int cur = t & 1, nxt = cur ^ 1;
    loadB((t + 1) * 16);
    issueA(nxt, (t + 1) * 64);
    compute(cur);
    writeB(nxt);
    __syncthreads();
  }
  // ---- tile 63 + low-rank extra K-step ----
  loadF();
  compute(1);
  writeF(0);
  __syncthreads();
  compute(0);

  // ---- epilogue: bias + store ----
#pragma unroll
  for (int fn = 0; fn < 2; ++fn) {
    int c = wn * 32 + fn * 16 + (lane & 15);
    int o = (c < 32) ? (o0 + c) : (HALF + o0 + (c - 32));
    float bv = bias[o];
#pragma unroll
    for (int fm = 0; fm < 4; ++fm) {
      int m = m0 + wm * 64 + fm * 16 + ((lane >> 4) << 2);
#pragma unroll
      for (int j = 0; j < 4; ++j)
        out[(size_t)(m + j) * OUT_F + o] = acc[fm][fn][j] + bv;
    }
  }
}

extern "C" void kernel_launch(void* const* d_in, const int* in_sizes, int n_in,
                              void* d_out, int out_size, void* d_ws, size_t ws_size,
                              hipStream_t stream) {
  const float* x     = (const float*)d_in[0];
  const int*   Wq    = (const int*)d_in[1];
  const float* scale = (const float*)d_in[2];
  const float* zero  = (const float*)d_in[3];
  const float* U     = (const float*)d_in[4];
  const float* V     = (const float*)d_in[5];
  const float* bias  = (const float*)d_in[6];
  float* out = (float*)d_out;

  unsigned short* xbf = (unsigned short*)d_ws;                 // 4 MB
  unsigned short* Ubf = xbf + (size_t)MROWS * IN_F;            // 704 KB
  float*          P   = (float*)(Ubf + (size_t)OUT_F * 32);    // 64 KB
  float*          mz  = P + (size_t)MROWS * 32;                // 2.82 MB

  (void)hipMemsetAsync(P, 0, (size_t)MROWS * 32 * sizeof(float), stream);
  convert_k<<<3080, 256, 0, stream>>>(x, U, scale, zero, xbf, Ubf, (f32x4*)mz);
  pcalc_k<<<512, 256, 0, stream>>>(x, V, P);
  milo_gemm<<<688, 256, 49152, stream>>>(xbf, (const i32x4*)Wq,
                                         (const f32x4*)scale, (const f32x4*)mz,
                                         P, (const i32x4*)Ubf, bias, out);
}

// Round 7
// 138.618 us; speedup vs baseline: 1.3644x; 1.0157x over previous
//
#include <hip/hip_runtime.h>
#include <cstdint>

typedef short  s16x8 __attribute__((ext_vector_type(8)));
typedef float  f32x4 __attribute__((ext_vector_type(4)));
typedef int    i32x4 __attribute__((ext_vector_type(4)));
typedef int    i32x2 __attribute__((ext_vector_type(2)));
typedef unsigned short u16x4 __attribute__((ext_vector_type(4)));

#define OUT_F 11008
#define IN_F  4096
#define MROWS 512
#define GQ4   176128   // i32x4 elements per W_q row (704512/4)
#define HALF  5504
#define RMOD  172

__device__ __forceinline__ unsigned short f2bf(float f) {
  unsigned u = __builtin_bit_cast(unsigned, f);
  return (unsigned short)((u + 0x8000u) >> 16);
}
__device__ __forceinline__ float bfbits(unsigned bits) {
  return __builtin_bit_cast(float, bits);
}
__device__ __forceinline__ unsigned cvtpk(float a, float b) {
  unsigned r;
  asm("v_cvt_pk_bf16_f32 %0, %1, %2" : "=v"(r) : "v"(a), "v"(b));
  return r;   // lo = bf16(a), hi = bf16(b)
}

// ---- prelude: bf16 x and U; f32 table mz = -(128+z)*s ----
__global__ __launch_bounds__(256) void convert_k(const float* __restrict__ x,
                                                 const float* __restrict__ U,
                                                 const float* __restrict__ scale,
                                                 const float* __restrict__ zero,
                                                 unsigned short* __restrict__ xbf,
                                                 unsigned short* __restrict__ Ubf,
                                                 f32x4* __restrict__ mz) {
  int i = blockIdx.x * 256 + threadIdx.x;
  const int NX = (MROWS * IN_F) / 4;   // 524288
  const int NU = (OUT_F * 32) / 4;     // 88064
  const int NS = 704512 / 4;           // 176128
  if (i < NX + NU) {
    const float* src; unsigned short* dst; int idx;
    if (i < NX) { src = x; dst = xbf; idx = i; }
    else        { src = U; dst = Ubf; idx = i - NX; }
    f32x4 v = *(const f32x4*)(src + (size_t)idx * 4);
    u16x4 o;
    o[0] = f2bf(v[0]); o[1] = f2bf(v[1]); o[2] = f2bf(v[2]); o[3] = f2bf(v[3]);
    *(u16x4*)(dst + (size_t)idx * 4) = o;
  } else {
    int idx = i - NX - NU;
    if (idx >= NS) return;
    f32x4 s = *(const f32x4*)(scale + (size_t)idx * 4);
    f32x4 z = *(const f32x4*)(zero  + (size_t)idx * 4);
    f32x4 m;
#pragma unroll
    for (int e = 0; e < 4; ++e) m[e] = -(z[e] + 128.f) * s[e];
    mz[idx] = m;
  }
}

// ---- prelude 2: P = x @ V^T (512x32), split-K atomics ----
__global__ __launch_bounds__(256) void pcalc_k(const float* __restrict__ x,
                                               const float* __restrict__ V,
                                               float* __restrict__ P) {
  int m  = (blockIdx.x >> 3) * 8 + (threadIdx.x >> 5);
  int j  = threadIdx.x & 31;
  int k0 = (blockIdx.x & 7) * 512;
  const float* xr = x + (size_t)m * IN_F + k0;
  const float* vr = V + (size_t)j * IN_F + k0;
  float a = 0.f;
#pragma unroll 4
  for (int k = 0; k < 512; k += 4) {
    f32x4 xv = *(const f32x4*)(xr + k);
    f32x4 vv = *(const f32x4*)(vr + k);
    a += xv[0]*vv[0] + xv[1]*vv[1] + xv[2]*vv[2] + xv[3]*vv[3];
  }
  atomicAdd(P + m * 32 + j, a);
}

// ---- main fused dequant GEMM ----
// Tile 128m x 64o. LDS 48KB: A dbuf [128][64]x2 + B dbuf [64][64]x2, swizzled.
// Grid 688 = 8 XCD x 86 contiguous-gn mapping (single-L2 W_q fetch).
// T4 pipeline: raw s_barrier + counted vmcnt (never 0 in steady loop);
// B-side regs prefetched 2 tiles deep (two NAMED regsets, pair-unrolled).
__global__ __launch_bounds__(256, 3) void milo_gemm(
    const unsigned short* __restrict__ xbf,
    const i32x4*          __restrict__ Wq4,
    const f32x4*          __restrict__ Sc4,
    const f32x4*          __restrict__ Mz4,
    const float*          __restrict__ Pf,
    const i32x4*          __restrict__ Ubf4,
    const float*          __restrict__ bias,
    float*                __restrict__ out)
{
  extern __shared__ __align__(16) unsigned short smem[];
  // A bufs: smem + buf*8192 shorts; B bufs: smem + 16384 + buf*4096 shorts

  const int tid  = threadIdx.x;
  const int lane = tid & 63;
  const int wid  = tid >> 6;
  const int wm   = wid >> 1;
  const int wn   = wid & 1;

  const int b  = blockIdx.x;
  const int L  = (b & 7) * 86 + (b >> 3);
  const int gn = L >> 2;          // 0..171
  const int gm = L & 3;           // 0..3
  const int m0 = gm * 128;
  const int o0 = gn * 32;

  unsigned wq_off[2], sc_off[2];
#pragma unroll
  for (int p = 0; p < 2; ++p) {
    int tr = (tid >> 4) + p * 16;
    int o  = o0 + tr;
    int g  = o / RMOD;
    int r  = o - g * RMOD;
    wq_off[p] = (unsigned)g * GQ4 + (unsigned)r * 1024u + (tid & 15);
    sc_off[p] = (unsigned)r * 1024u + (tid & 15);
  }
  unsigned a_src[4];
#pragma unroll
  for (int it = 0; it < 4; ++it) {
    int row   = it * 32 + wid * 8 + (lane >> 3);
    int chunk = (lane & 7) ^ ((lane >> 3) & 7);
    a_src[it] = (unsigned)(m0 + row) * IN_F + chunk * 8;
  }

  const int akey   = (lane & 7) << 3;
  const int a_base = (wm * 64 + (lane & 15)) * 64 + ((lane >> 4) * 8);
  const int b_base = (wn * 32 + (lane & 15)) * 64 + ((lane >> 4) * 8);

  f32x4 acc[4][2];
  {
    f32x4 zf = {0.f, 0.f, 0.f, 0.f};
#pragma unroll
    for (int i = 0; i < 4; ++i)
#pragma unroll
      for (int j = 0; j < 2; ++j) acc[i][j] = zf;
  }

  // two NAMED register staging sets (depth-2 prefetch; no runtime indexing)
  i32x4 wqS0[2], wqS1[2];
  f32x4 s4S0[2], mzS0[2], s4S1[2], mzS1[2];
  f32x4 pf[4]; i32x4 uuF;

  auto issueA = [&](int buf, int k0s) {
    unsigned short* Adst = smem + buf * 8192;
#pragma unroll
    for (int it = 0; it < 4; ++it) {
      __builtin_amdgcn_global_load_lds(
          (const __attribute__((address_space(1))) unsigned int*)(xbf + a_src[it] + k0s),
          (__attribute__((address_space(3))) unsigned int*)(Adst + (it * 32 + wid * 8) * 64),
          16, 0, 0);
    }
  };
  auto loadB = [&](int kq, i32x4 (&wq)[2], f32x4 (&s4)[2], f32x4 (&mz)[2]) {
#pragma unroll
    for (int p = 0; p < 2; ++p) {
      wq[p] = Wq4[wq_off[p] + kq];
      s4[p] = Sc4[sc_off[p] + kq];
      mz[p] = Mz4[sc_off[p] + kq];
    }
  };
  auto writeB = [&](int buf, const i32x4 (&wq)[2], const f32x4 (&s4)[2],
                    const f32x4 (&mz)[2]) {
    unsigned short* Bn = smem + 16384 + buf * 4096;
#pragma unroll
    for (int p = 0; p < 2; ++p) {
      int tr   = (tid >> 4) + p * 16;
      int scol = ((tid & 15) * 4) ^ ((tr & 7) << 3);
      float h[4], l[4];
#pragma unroll
      for (int e = 0; e < 4; ++e) {
        int v = wq[p][e];
        float qh = bfbits(0x43000000u | (((unsigned)v & 0xF0u) << 12));
        float ql = bfbits(0x43000000u | (((unsigned)v & 0x0Fu) << 16));
        h[e] = __builtin_fmaf(qh, s4[p][e], mz[p][e]);
        l[e] = __builtin_fmaf(ql, s4[p][e], mz[p][e]);
      }
      i32x2 hh = { (int)cvtpk(h[0], h[1]), (int)cvtpk(h[2], h[3]) };
      i32x2 ll = { (int)cvtpk(l[0], l[1]), (int)cvtpk(l[2], l[3]) };
      *(i32x2*)(Bn + tr * 64 + scol)        = hh;
      *(i32x2*)(Bn + (tr + 32) * 64 + scol) = ll;
    }
  };
  auto loadF = [&]() {
    int row = tid >> 1, h = tid & 1;
#pragma unroll
    for (int q = 0; q < 4; ++q)
      pf[q] = *(const f32x4*)(Pf + (m0 + row) * 32 + h * 16 + q * 4);
    int rw = tid >> 2, h4 = tid & 3;
    int oc = (rw < 32) ? (o0 + rw) : (HALF + o0 + rw - 32);
    uuF = Ubf4[oc * 4 + h4];
  };
  auto writeF = [&](int buf) {
    unsigned short* An = smem + buf * 8192;
    unsigned short* Bn = smem + 16384 + buf * 4096;
    i32x4 zi = {0, 0, 0, 0};
    {
      int row = tid >> 1, h = tid & 1;
      int key = (row & 7) << 3;
#pragma unroll
      for (int q = 0; q < 4; ++q) {
        i32x2 t2 = { (int)cvtpk(pf[q][0], pf[q][1]),
                     (int)cvtpk(pf[q][2], pf[q][3]) };
        *(i32x2*)(An + row * 64 + ((h * 16 + q * 4) ^ key)) = t2;
      }
#pragma unroll
      for (int q = 0; q < 2; ++q)
        *(i32x4*)(An + row * 64 + ((32 + h * 16 + q * 8) ^ key)) = zi;
    }
    {
      int rw = tid >> 2, h4 = tid & 3;
      int key = (rw & 7) << 3;
      *(i32x4*)(Bn + rw * 64 + ((h4 * 8) ^ key))      = uuF;
      *(i32x4*)(Bn + rw * 64 + ((32 + h4 * 8) ^ key)) = zi;
    }
  };
  auto compute = [&](int buf) {
    const unsigned short* Ac = smem + buf * 8192;
    const unsigned short* Bc = smem + 16384 + buf * 4096;
    __builtin_amdgcn_s_setprio(1);
#pragma unroll
    for (int kk = 0; kk < 64; kk += 32) {
      s16x8 av[4], bv[2];
#pragma unroll
      for (int f = 0; f < 4; ++f)
        av[f] = *(const s16x8*)(Ac + ((a_base + f * 1024 + kk) ^ akey));
#pragma unroll
      for (int f = 0; f < 2; ++f)
        bv[f] = *(const s16x8*)(Bc + ((b_base + f * 1024 + kk) ^ akey));
#pragma unroll
      for (int i = 0; i < 4; ++i)
#pragma unroll
        for (int j = 0; j < 2; ++j)
          acc[i][j] = __builtin_amdgcn_mfma_f32_16x16x32_bf16(av[i], bv[j], acc[i][j], 0, 0, 0);
    }
    __builtin_amdgcn_s_setprio(0);
  };

#define WAIT_LGKM0 asm volatile("s_waitcnt lgkmcnt(0)" ::: "memory")
#define WAIT_VM(N) asm volatile("s_waitcnt vmcnt(" #N ")" ::: "memory")

  // ---- prologue: tile0 staged; loadB(1) in flight ----
  issueA(0, 0);
  loadB(0,  wqS0, s4S0, mzS0);
  loadB(16, wqS1, s4S1, mzS1);
  writeB(0, wqS0, s4S0, mzS0);   // compiler vmcnt drains issueA(0)+loadB(0)
  WAIT_LGKM0;
  __builtin_amdgcn_s_barrier();

  // ---- main loop: t = 0..61, pair-unrolled (even: buf0, odd: buf1) ----
  for (int tt = 0; tt < 62; tt += 2) {
    // t = tt (even): compute buf0; stage tile t+1 -> buf1; load tile t+2 -> S0
    issueA(1, (tt + 1) * 64);
    writeB(1, wqS1, s4S1, mzS1);          // waits loadB(t+1) only (vmcnt 4)
    loadB((tt + 2) * 16, wqS0, s4S0, mzS0);
    compute(0);
    WAIT_LGKM0;
    WAIT_VM(6);                            // issueA done; loadB stays in flight
    __builtin_amdgcn_s_barrier();
    // t = tt+1 (odd): compute buf1; stage t+2 -> buf0; load t+3 -> S1
    issueA(0, (tt + 2) * 64);
    writeB(0, wqS0, s4S0, mzS0);
    loadB((tt + 3) * 16, wqS1, s4S1, mzS1);
    compute(1);
    WAIT_LGKM0;
    WAIT_VM(6);
    __builtin_amdgcn_s_barrier();
  }
  // ---- t = 62: last W tile staged (tile 63 -> buf1); no more loadB ----
  issueA(1, 63 * 64);
  writeB(1, wqS1, s4S1, mzS1);
  compute(0);
  WAIT_LGKM0;
  WAIT_VM(0);
  __builtin_amdgcn_s_barrier();
  // ---- t = 63: compute tile 63; stage low-rank tile -> buf0 ----
  loadF();
  compute(1);
  writeF(0);
  WAIT_LGKM0;
  __builtin_amdgcn_s_barrier();
  compute(0);   // low-rank K-step

  // ---- epilogue: bias + store ----
#pragma unroll
  for (int fn = 0; fn < 2; ++fn) {
    int c = wn * 32 + fn * 16 + (lane & 15);
    int o = (c < 32) ? (o0 + c) : (HALF + o0 + (c - 32));
    float bv = bias[o];
#pragma unroll
    for (int fm = 0; fm < 4; ++fm) {
      int m = m0 + wm * 64 + fm * 16 + ((lane >> 4) << 2);
#pragma unroll
      for (int j = 0; j < 4; ++j)
        out[(size_t)(m + j) * OUT_F + o] = acc[fm][fn][j] + bv;
    }
  }
#undef WAIT_LGKM0
#undef WAIT_VM
}

extern "C" void kernel_launch(void* const* d_in, const int* in_sizes, int n_in,
                              void* d_out, int out_size, void* d_ws, size_t ws_size,
                              hipStream_t stream) {
  const float* x     = (const float*)d_in[0];
  const int*   Wq    = (const int*)d_in[1];
  const float* scale = (const float*)d_in[2];
  const float* zero  = (const float*)d_in[3];
  const float* U     = (const float*)d_in[4];
  const float* V     = (const float*)d_in[5];
  const float* bias  = (const float*)d_in[6];
  float* out = (float*)d_out;

  unsigned short* xbf = (unsigned short*)d_ws;                 // 4 MB
  unsigned short* Ubf = xbf + (size_t)MROWS * IN_F;            // 704 KB
  float*          P   = (float*)(Ubf + (size_t)OUT_F * 32);    // 64 KB
  float*          mz  = P + (size_t)MROWS * 32;                // 2.82 MB

  (void)hipMemsetAsync(P, 0, (size_t)MROWS * 32 * sizeof(float), stream);
  convert_k<<<3080, 256, 0, stream>>>(x, U, scale, zero, xbf, Ubf, (f32x4*)mz);
  pcalc_k<<<512, 256, 0, stream>>>(x, V, P);
  milo_gemm<<<688, 256, 49152, stream>>>(xbf, (const i32x4*)Wq,
                                         (const f32x4*)scale, (const f32x4*)mz,
                                         P, (const i32x4*)Ubf, bias, out);
}